// Round 1
// baseline (179.159 us; speedup 1.0000x reference)
//
#include <hip/hip_runtime.h>
#include <cstdint>

// Problem constants
#define BB 8
#define LL 2048
#define DD 768
#define SS 512
#define MAXW 32

constexpr int M = BB * SS;   // 4096 spans
constexpr int K = 2 * DD;    // 1536
constexpr int N = DD;        // 768

// ---------------------------------------------------------------------------
// Kernel 1: per-span masked max + mean over the window [start, end]
// (reference semantics: mask = (r <= width) & (end - r >= 0); since
//  end >= start >= 0 and end >= width, all w in [0, width] are valid,
//  denom = width+1 = count, so it's a plain max/mean over the window rows)
// Output: cat[span][0:768] = max, cat[span][768:1536] = mean  (fp32, in d_ws)
// ---------------------------------------------------------------------------
__global__ __launch_bounds__(192) void span_feat_kernel(
    const float* __restrict__ repr,   // (B, L, D) f32
    const int*   __restrict__ spans,  // (B, S, 2) int
    float*       __restrict__ cat)    // (M, 2D) f32
{
    const int span = blockIdx.x;         // 0..M-1
    const int b    = span >> 9;          // span / S  (S = 512)
    const int t    = threadIdx.x;        // 0..191, one float4 (4 dims) each

    // Robustness hedge: detect int64-layout span indices (values < 2048 so
    // high words are 0). Under int32 layout, words 1,3,5,7 are ends[0..3],
    // all-zero with probability ~0. Wave-uniform branch, L2-cached loads.
    const bool is64 = ((spans[1] | spans[3] | spans[5] | spans[7]) == 0);
    int st, en;
    if (is64) { st = spans[4 * span];     en = spans[4 * span + 2]; }
    else      { st = spans[2 * span];     en = spans[2 * span + 1]; }
    const int width = en - st;           // 0..31, uniform across block

    const float4* base = (const float4*)repr + (size_t)b * LL * (DD / 4);

    float4 mx = make_float4(-3.0e38f, -3.0e38f, -3.0e38f, -3.0e38f);
    float4 sm = make_float4(0.f, 0.f, 0.f, 0.f);

    for (int w = 0; w <= width; ++w) {
        const float4 v = base[(size_t)(en - w) * (DD / 4) + t];
        mx.x = fmaxf(mx.x, v.x);  mx.y = fmaxf(mx.y, v.y);
        mx.z = fmaxf(mx.z, v.z);  mx.w = fmaxf(mx.w, v.w);
        sm.x += v.x;  sm.y += v.y;  sm.z += v.z;  sm.w += v.w;
    }

    const float inv = 1.0f / (float)(width + 1);
    float4* crow = (float4*)(cat + (size_t)span * K);
    crow[t] = mx;
    crow[DD / 4 + t] = make_float4(sm.x * inv, sm.y * inv, sm.z * inv, sm.w * inv);
}

// ---------------------------------------------------------------------------
// Kernel 2: C = cat (4096x1536) @ W_down (1536x768) + b_down, fp32 tiled.
// BM=BN=64, BK=16, 256 threads, 4x4 micro-tile per thread.
// ---------------------------------------------------------------------------
constexpr int BM = 64, BN = 64, BK = 16;

__global__ __launch_bounds__(256) void gemm_bias_kernel(
    const float* __restrict__ A,     // (M, K)
    const float* __restrict__ Wd,    // (K, N)
    const float* __restrict__ bias,  // (N)
    float*       __restrict__ C)     // (M, N)
{
    __shared__ float As[BK][BM + 4];  // A tile, transposed (k-major), padded
    __shared__ float Bs[BK][BN];      // B tile as-is (k rows, n cols)

    const int tid = threadIdx.x;
    const int m0 = blockIdx.x * BM;
    const int n0 = blockIdx.y * BN;

    const int tm = tid >> 4;          // 0..15 -> rows tm*4..tm*4+3
    const int tn = tid & 15;          // 0..15 -> cols tn*4..tn*4+3

    // Global-load index maps (one float4 per thread per tile)
    const int a_mr = tid >> 2;        // 0..63   (row within A tile)
    const int a_kg = (tid & 3) * 4;   // 0,4,8,12 (k group within A tile)
    const int b_kr = tid >> 4;        // 0..15   (k row within B tile)
    const int b_ng = (tid & 15) * 4;  // 0..60   (n group within B tile)

    float acc[4][4] = {};

    for (int k0 = 0; k0 < K; k0 += BK) {
        const float4 av = *(const float4*)(A  + (size_t)(m0 + a_mr) * K + k0 + a_kg);
        const float4 bv = *(const float4*)(Wd + (size_t)(k0 + b_kr) * N + n0 + b_ng);

        __syncthreads();   // previous iteration's compute done before overwrite
        As[a_kg + 0][a_mr] = av.x;
        As[a_kg + 1][a_mr] = av.y;
        As[a_kg + 2][a_mr] = av.z;
        As[a_kg + 3][a_mr] = av.w;
        *(float4*)&Bs[b_kr][b_ng] = bv;
        __syncthreads();

        #pragma unroll
        for (int kk = 0; kk < BK; ++kk) {
            const float4 ra = *(const float4*)&As[kk][tm * 4];
            const float4 rb = *(const float4*)&Bs[kk][tn * 4];
            acc[0][0] = fmaf(ra.x, rb.x, acc[0][0]);
            acc[0][1] = fmaf(ra.x, rb.y, acc[0][1]);
            acc[0][2] = fmaf(ra.x, rb.z, acc[0][2]);
            acc[0][3] = fmaf(ra.x, rb.w, acc[0][3]);
            acc[1][0] = fmaf(ra.y, rb.x, acc[1][0]);
            acc[1][1] = fmaf(ra.y, rb.y, acc[1][1]);
            acc[1][2] = fmaf(ra.y, rb.z, acc[1][2]);
            acc[1][3] = fmaf(ra.y, rb.w, acc[1][3]);
            acc[2][0] = fmaf(ra.z, rb.x, acc[2][0]);
            acc[2][1] = fmaf(ra.z, rb.y, acc[2][1]);
            acc[2][2] = fmaf(ra.z, rb.z, acc[2][2]);
            acc[2][3] = fmaf(ra.z, rb.w, acc[2][3]);
            acc[3][0] = fmaf(ra.w, rb.x, acc[3][0]);
            acc[3][1] = fmaf(ra.w, rb.y, acc[3][1]);
            acc[3][2] = fmaf(ra.w, rb.z, acc[3][2]);
            acc[3][3] = fmaf(ra.w, rb.w, acc[3][3]);
        }
    }

    // Epilogue: add bias, write 4x4 as float4 rows
    const float4 bv = *(const float4*)(bias + n0 + tn * 4);
    #pragma unroll
    for (int i = 0; i < 4; ++i) {
        float4 o;
        o.x = acc[i][0] + bv.x;
        o.y = acc[i][1] + bv.y;
        o.z = acc[i][2] + bv.z;
        o.w = acc[i][3] + bv.w;
        *(float4*)(C + (size_t)(m0 + tm * 4 + i) * N + n0 + tn * 4) = o;
    }
}

// ---------------------------------------------------------------------------
extern "C" void kernel_launch(void* const* d_in, const int* in_sizes, int n_in,
                              void* d_out, int out_size, void* d_ws, size_t ws_size,
                              hipStream_t stream)
{
    const float* repr  = (const float*)d_in[0];  // (B,L,D) f32
    const int*   spans = (const int*)  d_in[1];  // (B,S,2) int
    const float* Wd    = (const float*)d_in[2];  // (2D,D) f32
    const float* bias  = (const float*)d_in[3];  // (D)    f32
    float* out = (float*)d_out;                  // (B,S,D) f32
    float* cat = (float*)d_ws;                   // (M, 2D) f32 = 25.2 MB scratch

    span_feat_kernel<<<M, 192, 0, stream>>>(repr, spans, cat);

    dim3 grid(M / BM, N / BN);  // 64 x 12
    gemm_bias_kernel<<<grid, 256, 0, stream>>>(cat, Wd, bias, out);
}

// Round 2
// 64.691 us; speedup vs baseline: 2.7694x; 2.7694x over previous
//
#include <hip/hip_runtime.h>
#include <cstdint>

// Problem constants
#define BB 8
#define LL 2048
#define DD 768
#define SS 512
#define MAXW 32

constexpr int M = BB * SS;   // 4096 spans
constexpr int K = 2 * DD;    // 1536
constexpr int N = DD;        // 768

typedef __attribute__((ext_vector_type(8))) short short8;   // 8 bf16 = 4 VGPRs
typedef __attribute__((ext_vector_type(4))) float f32x4;

__device__ __forceinline__ unsigned short f2bf(float f) {
    union { float f; unsigned int u; } v; v.f = f;
    unsigned int r = v.u + 0x7fffu + ((v.u >> 16) & 1u);  // RNE
    return (unsigned short)(r >> 16);
}

// generic -> addrspace casts for global_load_lds
#define AS1(p) reinterpret_cast<const __attribute__((address_space(1))) void*>( \
                   reinterpret_cast<uintptr_t>(p))
#define AS3(p) reinterpret_cast<__attribute__((address_space(3))) void*>( \
                   reinterpret_cast<uintptr_t>(p))

// ---------------------------------------------------------------------------
// Kernel 1: per-span masked max + mean -> cat (bf16, M x 2D) in workspace
// ---------------------------------------------------------------------------
__global__ __launch_bounds__(192) void span_feat_kernel(
    const float* __restrict__ repr,          // (B, L, D) f32
    const int*   __restrict__ spans,         // (B, S, 2) int
    unsigned short* __restrict__ cat)        // (M, 2D) bf16
{
    const int span = blockIdx.x;
    const int b    = span >> 9;              // span / S
    const int t    = threadIdx.x;            // 0..191, one float4 each

    // int64-layout sniff (values < 2048 so high words zero under int64)
    const bool is64 = ((spans[1] | spans[3] | spans[5] | spans[7]) == 0);
    int st, en;
    if (is64) { st = spans[4 * span];     en = spans[4 * span + 2]; }
    else      { st = spans[2 * span];     en = spans[2 * span + 1]; }
    const int width = en - st;               // 0..31, block-uniform

    const float4* base = (const float4*)repr + (size_t)b * LL * (DD / 4);

    float4 mx = make_float4(-3.0e38f, -3.0e38f, -3.0e38f, -3.0e38f);
    float4 sm = make_float4(0.f, 0.f, 0.f, 0.f);

    for (int w = 0; w <= width; ++w) {
        const float4 v = base[(size_t)(en - w) * (DD / 4) + t];
        mx.x = fmaxf(mx.x, v.x);  mx.y = fmaxf(mx.y, v.y);
        mx.z = fmaxf(mx.z, v.z);  mx.w = fmaxf(mx.w, v.w);
        sm.x += v.x;  sm.y += v.y;  sm.z += v.z;  sm.w += v.w;
    }

    const float inv = 1.0f / (float)(width + 1);
    unsigned short* crow = cat + (size_t)span * K;
    ushort4 omax, omean;
    omax.x = f2bf(mx.x); omax.y = f2bf(mx.y); omax.z = f2bf(mx.z); omax.w = f2bf(mx.w);
    omean.x = f2bf(sm.x * inv); omean.y = f2bf(sm.y * inv);
    omean.z = f2bf(sm.z * inv); omean.w = f2bf(sm.w * inv);
    *(ushort4*)(crow + t * 4)      = omax;
    *(ushort4*)(crow + DD + t * 4) = omean;
}

// ---------------------------------------------------------------------------
// Kernel 2: W_down (K x N f32) -> WT (N x K bf16), LDS-tiled transpose+cast
// ---------------------------------------------------------------------------
__global__ __launch_bounds__(256) void wt_kernel(
    const float* __restrict__ W, unsigned short* __restrict__ WT)
{
    __shared__ float t[32][33];
    const int n0 = blockIdx.x * 32, k0 = blockIdx.y * 32;
    const int tx = threadIdx.x, ty = threadIdx.y;   // (32, 8)
    #pragma unroll
    for (int j = 0; j < 4; ++j)
        t[ty + 8 * j][tx] = W[(size_t)(k0 + ty + 8 * j) * N + n0 + tx];
    __syncthreads();
    #pragma unroll
    for (int j = 0; j < 4; ++j)
        WT[(size_t)(n0 + ty + 8 * j) * K + k0 + tx] = f2bf(t[tx][ty + 8 * j]);
}

// ---------------------------------------------------------------------------
// Kernel 3: out = cat(bf16) @ W(bf16) + bias, MFMA 16x16x32.
// BM=128, BN=96, BK=64; 256 threads = 4 waves (2x2); wave tile 64x48.
// global_load_lds (16B) with pre-swizzled global source; XOR-swizzled reads.
// ---------------------------------------------------------------------------
constexpr int BM = 128, BN = 96, BK = 64;

__global__ __launch_bounds__(256) void gemm_bias_kernel(
    const unsigned short* __restrict__ A,    // (M, K)  bf16
    const unsigned short* __restrict__ WT,   // (N, K)  bf16
    const float* __restrict__ bias,          // (N)     f32
    float*       __restrict__ C)             // (M, N)  f32
{
    __shared__ unsigned short Asm[BM * BK];  // 128 rows x 8 chunks(16B), swizzled
    __shared__ unsigned short Bsm[BN * BK];  //  96 rows x 8 chunks

    const int tid = threadIdx.x;
    const int m0 = blockIdx.x * BM;
    const int n0 = blockIdx.y * BN;

    const int lane = tid & 63;
    const int wid  = tid >> 6;
    const int wm = wid >> 1, wn = wid & 1;   // 2x2 wave grid
    const int lnib = lane & 15, hi = lane >> 4;

    f32x4 acc[4][3] = {};

    for (int k0 = 0; k0 < K; k0 += BK) {
        __syncthreads();  // previous compute done before LDS overwrite
        // ---- stage A: 1024 chunks, 4 per thread; LDS linear, source swizzled
        #pragma unroll
        for (int it = 0; it < 4; ++it) {
            const int s   = it * 256 + tid;
            const int row = s >> 3, c8 = s & 7;
            const unsigned short* g =
                A + (size_t)(m0 + row) * K + k0 + ((c8 ^ (row & 7)) << 3);
            __builtin_amdgcn_global_load_lds(AS1(g), AS3(&Asm[s << 3]), 16, 0, 0);
        }
        // ---- stage B: 768 chunks, 3 per thread
        #pragma unroll
        for (int it = 0; it < 3; ++it) {
            const int s   = it * 256 + tid;
            const int row = s >> 3, c8 = s & 7;
            const unsigned short* g =
                WT + (size_t)(n0 + row) * K + k0 + ((c8 ^ (row & 7)) << 3);
            __builtin_amdgcn_global_load_lds(AS1(g), AS3(&Bsm[s << 3]), 16, 0, 0);
        }
        __syncthreads();  // barrier drain includes vmcnt(0)

        #pragma unroll
        for (int kk = 0; kk < 2; ++kk) {
            short8 af[4], bf[3];
            const int cc = kk * 4 + hi;
            #pragma unroll
            for (int mf = 0; mf < 4; ++mf) {
                const int r = wm * 64 + mf * 16 + lnib;
                af[mf] = *(const short8*)&Asm[(r * 8 + (cc ^ (r & 7))) << 3];
            }
            #pragma unroll
            for (int nf = 0; nf < 3; ++nf) {
                const int r = wn * 48 + nf * 16 + lnib;
                bf[nf] = *(const short8*)&Bsm[(r * 8 + (cc ^ (r & 7))) << 3];
            }
            #pragma unroll
            for (int mf = 0; mf < 4; ++mf)
                #pragma unroll
                for (int nf = 0; nf < 3; ++nf)
                    acc[mf][nf] = __builtin_amdgcn_mfma_f32_16x16x32_bf16(
                        af[mf], bf[nf], acc[mf][nf], 0, 0, 0);
        }
    }

    // Epilogue: bias + store. C/D layout: col = lane&15, row = hi*4 + reg.
    #pragma unroll
    for (int nf = 0; nf < 3; ++nf) {
        const int col = n0 + wn * 48 + nf * 16 + lnib;
        const float bv = bias[col];
        #pragma unroll
        for (int mf = 0; mf < 4; ++mf) {
            const int rbase = m0 + wm * 64 + mf * 16 + hi * 4;
            #pragma unroll
            for (int r = 0; r < 4; ++r)
                C[(size_t)(rbase + r) * N + col] = acc[mf][nf][r] + bv;
        }
    }
}

// ---------------------------------------------------------------------------
extern "C" void kernel_launch(void* const* d_in, const int* in_sizes, int n_in,
                              void* d_out, int out_size, void* d_ws, size_t ws_size,
                              hipStream_t stream)
{
    const float* repr  = (const float*)d_in[0];  // (B,L,D) f32
    const int*   spans = (const int*)  d_in[1];  // (B,S,2)
    const float* Wd    = (const float*)d_in[2];  // (2D,D) f32
    const float* bias  = (const float*)d_in[3];  // (D)    f32
    float* out = (float*)d_out;                  // (M, N) f32

    unsigned short* catb = (unsigned short*)d_ws;             // M*K bf16 = 12.6 MB
    unsigned short* WT   = catb + (size_t)M * K;              // N*K bf16 = 2.36 MB

    span_feat_kernel<<<M, 192, 0, stream>>>(repr, spans, catb);

    dim3 tgrid(N / 32, K / 32);                  // 24 x 48
    wt_kernel<<<tgrid, dim3(32, 8), 0, stream>>>(Wd, WT);

    dim3 ggrid(M / BM, N / BN);                  // 32 x 8 = 256 blocks
    gemm_bias_kernel<<<ggrid, 256, 0, stream>>>(catb, WT, bias, out);
}

// Round 3
// 52.946 us; speedup vs baseline: 3.3838x; 1.2218x over previous
//
#include <hip/hip_runtime.h>
#include <cstdint>

// Problem constants
#define BB 8
#define LL 2048
#define DD 768
#define SS 512
#define MAXW 32

constexpr int M = BB * SS;   // 4096 spans
constexpr int K = 2 * DD;    // 1536
constexpr int N = DD;        // 768

typedef __attribute__((ext_vector_type(8))) short short8;   // 8 bf16 = 4 VGPRs
typedef __attribute__((ext_vector_type(4))) float f32x4;

__device__ __forceinline__ unsigned short f2bf(float f) {
    union { float f; unsigned int u; } v; v.f = f;
    unsigned int r = v.u + 0x7fffu + ((v.u >> 16) & 1u);  // RNE
    return (unsigned short)(r >> 16);
}
__device__ __forceinline__ float bf2f(unsigned short u) {
    union { unsigned int u; float f; } v; v.u = ((unsigned int)u) << 16;
    return v.f;
}

// generic -> addrspace casts for global_load_lds
#define AS1(p) reinterpret_cast<const __attribute__((address_space(1))) void*>( \
                   reinterpret_cast<uintptr_t>(p))
#define AS3(p) reinterpret_cast<__attribute__((address_space(3))) void*>( \
                   reinterpret_cast<uintptr_t>(p))

// ---------------------------------------------------------------------------
// Kernel 1 (fused): blocks [0,2048): repr f32 -> bf16, batch b = bid&7 so each
// batch's bf16 slice (3.07 MB < 4 MB) lands in XCD b's L2.
// Blocks [2048, 2048+1152): W_down (K x N f32) -> WT (N x K bf16) transpose.
// ---------------------------------------------------------------------------
__global__ __launch_bounds__(256) void prep_kernel(
    const float* __restrict__ repr,          // (B,L,D) f32
    unsigned short* __restrict__ reprb,      // (B,L,D) bf16
    const float* __restrict__ W,             // (K,N) f32
    unsigned short* __restrict__ WT)         // (N,K) bf16
{
    __shared__ float tbuf[32][33];
    const int bid = blockIdx.x;
    const int tid = threadIdx.x;

    if (bid < 2048) {
        // convert: batch b, chunk c (256 chunks/batch of 6144 floats)
        const int b = bid & 7, c = bid >> 3;
        const size_t base = (size_t)b * (LL * DD) + (size_t)c * 6144;
        const float4* src = (const float4*)(repr + base);
        ushort4* dst = (ushort4*)(reprb + base);
        #pragma unroll
        for (int i = 0; i < 6; ++i) {
            const float4 v = src[i * 256 + tid];
            ushort4 o;
            o.x = f2bf(v.x); o.y = f2bf(v.y); o.z = f2bf(v.z); o.w = f2bf(v.w);
            dst[i * 256 + tid] = o;
        }
    } else {
        // transpose+cast W: 24 x 48 tiles of 32x32
        const int t = bid - 2048;
        const int n0 = (t % 24) * 32, k0 = (t / 24) * 32;
        const int tx = tid & 31, ty = tid >> 5;      // (32, 8)
        #pragma unroll
        for (int j = 0; j < 4; ++j)
            tbuf[ty + 8 * j][tx] = W[(size_t)(k0 + ty + 8 * j) * N + n0 + tx];
        __syncthreads();
        #pragma unroll
        for (int j = 0; j < 4; ++j)
            WT[(size_t)(n0 + ty + 8 * j) * K + k0 + tx] = f2bf(tbuf[tx][ty + 8 * j]);
    }
}

// ---------------------------------------------------------------------------
// Kernel 2: per-span masked max + mean over [start, end], reading bf16 repr
// from the batch-local XCD L2. bid&7 = batch -> XCD pin.
// cat[span][0:768] = max, [768:1536] = mean  (bf16)
// ---------------------------------------------------------------------------
__global__ __launch_bounds__(192) void span_feat_kernel(
    const unsigned short* __restrict__ reprb,  // (B,L,D) bf16
    const int*   __restrict__ spans,           // (B,S,2) int
    unsigned short* __restrict__ cat)          // (M, 2D) bf16
{
    const int bid = blockIdx.x;
    const int b = bid & 7, s = bid >> 3;
    const int span = (b << 9) | s;
    const int t = threadIdx.x;                 // 0..191, 4 dims each

    // int64-layout sniff (values < 2048 so high words zero under int64)
    const bool is64 = ((spans[1] | spans[3] | spans[5] | spans[7]) == 0);
    int st, en;
    if (is64) { st = spans[4 * span];     en = spans[4 * span + 2]; }
    else      { st = spans[2 * span];     en = spans[2 * span + 1]; }
    const int width = en - st;                 // 0..31, block-uniform

    const ushort4* base = (const ushort4*)reprb + (size_t)b * LL * (DD / 4);

    float4 mx = make_float4(-3.0e38f, -3.0e38f, -3.0e38f, -3.0e38f);
    float4 sm = make_float4(0.f, 0.f, 0.f, 0.f);

    for (int w = 0; w <= width; ++w) {
        const ushort4 u = base[(size_t)(en - w) * (DD / 4) + t];
        const float vx = bf2f(u.x), vy = bf2f(u.y), vz = bf2f(u.z), vw = bf2f(u.w);
        mx.x = fmaxf(mx.x, vx);  mx.y = fmaxf(mx.y, vy);
        mx.z = fmaxf(mx.z, vz);  mx.w = fmaxf(mx.w, vw);
        sm.x += vx;  sm.y += vy;  sm.z += vz;  sm.w += vw;
    }

    const float inv = 1.0f / (float)(width + 1);
    unsigned short* crow = cat + (size_t)span * K;
    ushort4 omax, omean;
    omax.x = f2bf(mx.x); omax.y = f2bf(mx.y); omax.z = f2bf(mx.z); omax.w = f2bf(mx.w);
    omean.x = f2bf(sm.x * inv); omean.y = f2bf(sm.y * inv);
    omean.z = f2bf(sm.z * inv); omean.w = f2bf(sm.w * inv);
    *(ushort4*)(crow + t * 4)      = omax;
    *(ushort4*)(crow + DD + t * 4) = omean;
}

// ---------------------------------------------------------------------------
// Kernel 3: out = cat(bf16) @ WT(bf16)^T + bias, MFMA 16x16x32.
// BM=BN=BK=64; 256 threads = 4 waves (2x2); wave tile 32x32.
// grid 768 = 3 blocks/CU; bijective XCD swizzle for A-panel L2 reuse.
// ---------------------------------------------------------------------------
constexpr int BM = 64, BN = 64, BK = 64;

__global__ __launch_bounds__(256) void gemm_bias_kernel(
    const unsigned short* __restrict__ A,    // (M, K)  bf16
    const unsigned short* __restrict__ WT,   // (N, K)  bf16
    const float* __restrict__ bias,          // (N)     f32
    float*       __restrict__ C)             // (M, N)  f32
{
    __shared__ unsigned short Asm[BM * BK];  // 8 KB, row-major chunks, swizzled
    __shared__ unsigned short Bsm[BN * BK];  // 8 KB

    const int tid = threadIdx.x;
    // XCD swizzle: 768 % 8 == 0 -> tile = (bid%8)*96 + bid/8
    const int tile = (blockIdx.x & 7) * 96 + (blockIdx.x >> 3);
    const int mt = tile / 12, nt = tile % 12;   // 64 x 12 tile grid
    const int m0 = mt * BM, n0 = nt * BN;

    const int lane = tid & 63;
    const int wid  = tid >> 6;
    const int wm = wid >> 1, wn = wid & 1;   // 2x2 wave grid, wave tile 32x32
    const int lnib = lane & 15, hi = lane >> 4;

    f32x4 acc[2][2] = {};

    for (int k0 = 0; k0 < K; k0 += BK) {
        __syncthreads();  // previous compute done before LDS overwrite
        // ---- stage A: 512 chunks (16B), 2 per thread; LDS linear, src swizzled
        #pragma unroll
        for (int it = 0; it < 2; ++it) {
            const int s   = it * 256 + tid;
            const int row = s >> 3, c8 = s & 7;
            const unsigned short* g =
                A + (size_t)(m0 + row) * K + k0 + ((c8 ^ (row & 7)) << 3);
            __builtin_amdgcn_global_load_lds(AS1(g), AS3(&Asm[s << 3]), 16, 0, 0);
        }
        // ---- stage B: 512 chunks, 2 per thread
        #pragma unroll
        for (int it = 0; it < 2; ++it) {
            const int s   = it * 256 + tid;
            const int row = s >> 3, c8 = s & 7;
            const unsigned short* g =
                WT + (size_t)(n0 + row) * K + k0 + ((c8 ^ (row & 7)) << 3);
            __builtin_amdgcn_global_load_lds(AS1(g), AS3(&Bsm[s << 3]), 16, 0, 0);
        }
        __syncthreads();  // barrier drain includes vmcnt(0)

        #pragma unroll
        for (int kk = 0; kk < 2; ++kk) {
            short8 af[2], bf[2];
            const int cc = kk * 4 + hi;
            #pragma unroll
            for (int mf = 0; mf < 2; ++mf) {
                const int r = wm * 32 + mf * 16 + lnib;
                af[mf] = *(const short8*)&Asm[(r * 8 + (cc ^ (r & 7))) << 3];
            }
            #pragma unroll
            for (int nf = 0; nf < 2; ++nf) {
                const int r = wn * 32 + nf * 16 + lnib;
                bf[nf] = *(const short8*)&Bsm[(r * 8 + (cc ^ (r & 7))) << 3];
            }
            #pragma unroll
            for (int mf = 0; mf < 2; ++mf)
                #pragma unroll
                for (int nf = 0; nf < 2; ++nf)
                    acc[mf][nf] = __builtin_amdgcn_mfma_f32_16x16x32_bf16(
                        af[mf], bf[nf], acc[mf][nf], 0, 0, 0);
        }
    }

    // Epilogue: bias + store. C/D layout: col = lane&15, row = hi*4 + reg.
    #pragma unroll
    for (int nf = 0; nf < 2; ++nf) {
        const int col = n0 + wn * 32 + nf * 16 + lnib;
        const float bv = bias[col];
        #pragma unroll
        for (int mf = 0; mf < 2; ++mf) {
            const int rbase = m0 + wm * 32 + mf * 16 + hi * 4;
            #pragma unroll
            for (int r = 0; r < 4; ++r)
                C[(size_t)(rbase + r) * N + col] = acc[mf][nf][r] + bv;
        }
    }
}

// ---------------------------------------------------------------------------
extern "C" void kernel_launch(void* const* d_in, const int* in_sizes, int n_in,
                              void* d_out, int out_size, void* d_ws, size_t ws_size,
                              hipStream_t stream)
{
    const float* repr  = (const float*)d_in[0];  // (B,L,D) f32
    const int*   spans = (const int*)  d_in[1];  // (B,S,2)
    const float* Wd    = (const float*)d_in[2];  // (2D,D) f32
    const float* bias  = (const float*)d_in[3];  // (D)    f32
    float* out = (float*)d_out;                  // (M, N) f32

    unsigned short* catb  = (unsigned short*)d_ws;            // M*K   = 12.6 MB
    unsigned short* WT    = catb + (size_t)M * K;             // N*K   =  2.4 MB
    unsigned short* reprb = WT   + (size_t)N * K;             // B*L*D = 25.2 MB

    prep_kernel<<<2048 + 1152, 256, 0, stream>>>(repr, reprb, Wd, WT);
    span_feat_kernel<<<M, 192, 0, stream>>>(reprb, spans, catb);
    gemm_bias_kernel<<<768, 256, 0, stream>>>(catb, WT, bias, out);
}